// Round 1
// baseline (2798.295 us; speedup 1.0000x reference)
//
#include <hip/hip_runtime.h>
#include <hip/hip_bf16.h>

static constexpr int Bn = 32;
static constexpr int Tn = 4096;
static constexpr int Dn = 256;
static constexpr int Un = 256;

// K1: qb[b][u] = sum_d query[b][d]*W2[d][u] + b1[u] + b2[u]
__global__ __launch_bounds__(256) void k_qproj(const float* __restrict__ query,
                                               const float* __restrict__ W2,
                                               const float* __restrict__ b1,
                                               const float* __restrict__ b2,
                                               float* __restrict__ qb) {
    __shared__ float qs[Dn];
    const int b = blockIdx.x, u = threadIdx.x;
    qs[u] = query[b * Dn + u];
    __syncthreads();
    float acc = b1[u] + b2[u];
    #pragma unroll 8
    for (int d = 0; d < Dn; ++d) acc += qs[d] * W2[d * Un + u];
    qb[b * Un + u] = acc;
}

// K2: fused score GEMM. Per block: 64 t-rows x full U=256, fp32 register tile.
// Thread (ul=tid&63, tg=tid>>6) owns 16 t x 4 u. Epilogue: tanh, dot with V,
// wave-reduce over the 64 u-lanes -> score[b][t].
__global__ __launch_bounds__(256) void k_score(const float* __restrict__ values,
                                               const float* __restrict__ W1,
                                               const float* __restrict__ qb,
                                               const float* __restrict__ Vw,
                                               const float* __restrict__ bV,
                                               float* __restrict__ scores) {
    __shared__ __align__(16) float Vt[64][36];   // values tile [t][d-chunk 32], pad->36 (144B row, 16B-aligned)
    __shared__ __align__(16) float Wt[32][256];  // W1 tile [d-chunk][U]
    const int tid = threadIdx.x;
    const int b = blockIdx.y;
    const int t0 = blockIdx.x * 64;
    const int ul = tid & 63, tg = tid >> 6;
    const int u0 = ul * 4, tbase = tg * 16;

    const float4 qb4 = *(const float4*)&qb[b * Un + u0];
    float4 acc[16];
    #pragma unroll
    for (int tt = 0; tt < 16; ++tt) acc[tt] = qb4;  // bias folded into accumulator init

    const float* vbase = values + ((size_t)b * Tn + t0) * Dn;

    for (int d0 = 0; d0 < Dn; d0 += 32) {
        // stage values tile: 64 rows x 32 d = 512 float4
        #pragma unroll
        for (int i = 0; i < 2; ++i) {
            int f = i * 256 + tid;
            int t = f >> 3, dj = (f & 7) * 4;
            *(float4*)&Vt[t][dj] = *(const float4*)&vbase[t * Dn + d0 + dj];
        }
        // stage W1 tile: 32 d x 256 u = 2048 float4
        #pragma unroll
        for (int i = 0; i < 8; ++i) {
            int f = i * 256 + tid;
            int dd = f >> 6, uj = (f & 63) * 4;
            *(float4*)&Wt[dd][uj] = *(const float4*)&W1[(d0 + dd) * Un + uj];
        }
        __syncthreads();
        #pragma unroll
        for (int dd = 0; dd < 32; dd += 4) {
            const float4 w0 = *(const float4*)&Wt[dd + 0][u0];
            const float4 w1 = *(const float4*)&Wt[dd + 1][u0];
            const float4 w2 = *(const float4*)&Wt[dd + 2][u0];
            const float4 w3 = *(const float4*)&Wt[dd + 3][u0];
            #pragma unroll
            for (int tt = 0; tt < 16; ++tt) {
                const float4 v = *(const float4*)&Vt[tbase + tt][dd];  // wave-broadcast
                acc[tt].x += v.x * w0.x + v.y * w1.x + v.z * w2.x + v.w * w3.x;
                acc[tt].y += v.x * w0.y + v.y * w1.y + v.z * w2.y + v.w * w3.y;
                acc[tt].z += v.x * w0.z + v.y * w1.z + v.z * w2.z + v.w * w3.z;
                acc[tt].w += v.x * w0.w + v.y * w1.w + v.z * w2.w + v.w * w3.w;
            }
        }
        __syncthreads();
    }

    const float4 vv = *(const float4*)&Vw[u0];
    const float bv = bV[0];
    #pragma unroll
    for (int tt = 0; tt < 16; ++tt) {
        float p = tanhf(acc[tt].x) * vv.x + tanhf(acc[tt].y) * vv.y
                + tanhf(acc[tt].z) * vv.z + tanhf(acc[tt].w) * vv.w;
        #pragma unroll
        for (int off = 32; off > 0; off >>= 1) p += __shfl_xor(p, off, 64);
        if (ul == 0) scores[b * Tn + t0 + tbase + tt] = p + bv;
    }
}

// K3: softmax over T per batch, in place (scores buffer == attn output region).
__global__ __launch_bounds__(256) void k_softmax(const float* __restrict__ scores,
                                                 float* __restrict__ attn) {
    const int b = blockIdx.x, tid = threadIdx.x;
    __shared__ float redm[4];
    __shared__ float reds[4];
    float s[16];
    float m = -1e30f;
    #pragma unroll
    for (int k = 0; k < 16; ++k) {
        s[k] = scores[b * Tn + k * 256 + tid];
        m = fmaxf(m, s[k]);
    }
    #pragma unroll
    for (int off = 32; off > 0; off >>= 1) m = fmaxf(m, __shfl_xor(m, off, 64));
    const int wid = tid >> 6;
    if ((tid & 63) == 0) redm[wid] = m;
    __syncthreads();
    m = fmaxf(fmaxf(redm[0], redm[1]), fmaxf(redm[2], redm[3]));
    float sum = 0.f;
    #pragma unroll
    for (int k = 0; k < 16; ++k) { s[k] = __expf(s[k] - m); sum += s[k]; }
    #pragma unroll
    for (int off = 32; off > 0; off >>= 1) sum += __shfl_xor(sum, off, 64);
    if ((tid & 63) == 0) reds[wid] = sum;
    __syncthreads();
    sum = reds[0] + reds[1] + reds[2] + reds[3];
    const float inv = 1.0f / sum;
    #pragma unroll
    for (int k = 0; k < 16; ++k) attn[b * Tn + k * 256 + tid] = s[k] * inv;
}

// K4: context partials. Block (c,b) reduces T/8 rows; thread (d4,tg) does
// float4 of d, t strided by 4. Deterministic (no atomics).
__global__ __launch_bounds__(256) void k_ctx_partial(const float* __restrict__ values,
                                                     const float* __restrict__ attn,
                                                     float* __restrict__ partial) {
    const int c = blockIdx.x, b = blockIdx.y, tid = threadIdx.x;
    const int d4 = (tid & 63) * 4, tg = tid >> 6;
    float4 a = make_float4(0.f, 0.f, 0.f, 0.f);
    const float* vbase = values + (size_t)b * Tn * Dn;
    const int tstart = c * (Tn / 8);
    for (int t = tstart + tg; t < tstart + Tn / 8; t += 4) {
        const float w = attn[b * Tn + t];                       // wave-uniform
        const float4 v = *(const float4*)&vbase[(size_t)t * Dn + d4];
        a.x += w * v.x; a.y += w * v.y; a.z += w * v.z; a.w += w * v.w;
    }
    __shared__ float4 red[4][64];
    red[tg][tid & 63] = a;
    __syncthreads();
    if (tg == 0) {
        const float4 r0 = red[0][tid], r1 = red[1][tid], r2 = red[2][tid], r3 = red[3][tid];
        a.x = r0.x + r1.x + r2.x + r3.x;
        a.y = r0.y + r1.y + r2.y + r3.y;
        a.z = r0.z + r1.z + r2.z + r3.z;
        a.w = r0.w + r1.w + r2.w + r3.w;
        *(float4*)&partial[(b * 8 + c) * Dn + d4] = a;
    }
}

// K5: reduce the 8 partials per batch.
__global__ __launch_bounds__(256) void k_ctx_final(const float* __restrict__ partial,
                                                   float* __restrict__ context) {
    const int b = blockIdx.x, d = threadIdx.x;
    float a = 0.f;
    #pragma unroll
    for (int c = 0; c < 8; ++c) a += partial[(b * 8 + c) * Dn + d];
    context[b * Dn + d] = a;
}

extern "C" void kernel_launch(void* const* d_in, const int* in_sizes, int n_in,
                              void* d_out, int out_size, void* d_ws, size_t ws_size,
                              hipStream_t stream) {
    const float* query  = (const float*)d_in[0];
    const float* values = (const float*)d_in[1];
    const float* W1     = (const float*)d_in[2];
    const float* b1     = (const float*)d_in[3];
    const float* W2     = (const float*)d_in[4];
    const float* b2     = (const float*)d_in[5];
    const float* Vw     = (const float*)d_in[6];
    const float* bV     = (const float*)d_in[7];

    float* context = (float*)d_out;            // [B,D]
    float* attn    = (float*)d_out + Bn * Dn;  // [B,T,1] — also used as score scratch
    float* partial = (float*)d_ws;             // [B,8,D]
    float* qb      = partial + Bn * 8 * Dn;    // [B,U]

    k_qproj<<<dim3(Bn), dim3(256), 0, stream>>>(query, W2, b1, b2, qb);
    // scores written into the attn region of d_out, softmaxed in place (K3
    // reads its 16 elements into registers before overwriting them).
    k_score<<<dim3(Tn / 64, Bn), dim3(256), 0, stream>>>(values, W1, qb, Vw, bV, attn);
    k_softmax<<<dim3(Bn), dim3(256), 0, stream>>>(attn, attn);
    k_ctx_partial<<<dim3(8, Bn), dim3(256), 0, stream>>>(values, attn, partial);
    k_ctx_final<<<dim3(Bn), dim3(256), 0, stream>>>(partial, context);
}

// Round 2
// 95.555 us; speedup vs baseline: 29.2848x; 29.2848x over previous
//
#include <hip/hip_runtime.h>
#include <hip/hip_bf16.h>

typedef __attribute__((ext_vector_type(4))) float f32x4;
typedef __attribute__((ext_vector_type(8))) short s16x8;

static constexpr int Bn = 32;
static constexpr int Tn = 4096;
static constexpr int Dn = 256;
static constexpr int Un = 256;
static constexpr int CTX_C = 16;

// fp32 -> bf16 round-to-nearest-even (inputs are finite, no NaN handling needed)
__device__ __forceinline__ ushort f2bf(float f) {
    unsigned x = __float_as_uint(f);
    x += 0x7fffu + ((x >> 16) & 1u);
    return (ushort)(x >> 16);
}

// stable fast tanh: tanh(x) = sign(x) * (1 - e) / (1 + e), e = exp(-2|x|)
__device__ __forceinline__ float fast_tanh(float x) {
    float ax = fabsf(x);
    float e = __expf(-2.0f * ax);
    float r = __fdividef(1.0f - e, 1.0f + e);
    return copysignf(r, x);
}

__device__ __forceinline__ void gload_lds16(const void* g, void* l) {
    __builtin_amdgcn_global_load_lds(
        (const __attribute__((address_space(1))) unsigned*)g,
        (__attribute__((address_space(3))) unsigned*)l, 16, 0, 0);
}

// K0: W1T[u][d] = bf16(W1[d][u])  (256 KB once; L2-resident afterwards)
__global__ __launch_bounds__(256) void k_w1t(const float* __restrict__ W1,
                                             ushort* __restrict__ W1T) {
    const int u = blockIdx.x, d = threadIdx.x;
    W1T[u * Dn + d] = f2bf(W1[d * Un + u]);
}

// K1: qb[b][u] = sum_d query[b][d]*W2[d][u] + b1[u] + b2[u]   (fp32, tiny)
__global__ __launch_bounds__(256) void k_qproj(const float* __restrict__ query,
                                               const float* __restrict__ W2,
                                               const float* __restrict__ b1,
                                               const float* __restrict__ b2,
                                               float* __restrict__ qb) {
    __shared__ float qs[Dn];
    const int b = blockIdx.x, u = threadIdx.x;
    qs[u] = query[b * Dn + u];
    __syncthreads();
    float acc = b1[u] + b2[u];
    #pragma unroll 8
    for (int d = 0; d < Dn; ++d) acc += qs[d] * W2[d * Un + u];
    qb[b * Un + u] = acc;
}

// K2: MFMA score GEMM. Block: 64 t x 256 u, 4 waves (16 t each).
// A = values tile (fp32->bf16 staged once, +16B row pad -> 2-way LDS conflicts only).
// B = W1T chunks via global_load_lds (linear dest). K-slot mapping of A/B frags is
// self-consistent (same per-lane k enumeration), so result is exact GEMM regardless
// of HW K-order. Epilogue: tanh -> dot V -> shuffle-reduce over 16 u-lanes.
__global__ __launch_bounds__(256, 2) void k_score(const float* __restrict__ values,
                                                  const ushort* __restrict__ W1T,
                                                  const float* __restrict__ qb,
                                                  const float* __restrict__ Vw,
                                                  const float* __restrict__ bV,
                                                  float* __restrict__ scores) {
    __shared__ __align__(16) ushort Al[64][264];   // 33.8 KB, 528B rows (528/16=33 odd -> bank spread)
    __shared__ __align__(16) ushort Bl[256][32];   // 16 KB, [u][k-chunk]
    const int tid = threadIdx.x;
    const int b = blockIdx.y;
    const int t0 = blockIdx.x * 64;
    const int wid = tid >> 6;
    const int lane = tid & 63;
    const int l15 = lane & 15;
    const int hi = lane >> 4;

    // epilogue vectors: this lane's u-column per u-tile
    float Vreg[16], qreg[16];
    #pragma unroll
    for (int ut = 0; ut < 16; ++ut) {
        int u = ut * 16 + l15;
        Vreg[ut] = Vw[u];
        qreg[ut] = qb[b * Un + u];
    }

    // Stage A: 64 rows x 256 d, fp32 read (coalesced 32B/lane) -> bf16 RNE -> LDS
    const float* vbase = values + ((size_t)b * Tn + t0) * Dn;
    #pragma unroll
    for (int i = 0; i < 8; ++i) {
        int flat = i * 2048 + tid * 8;
        int row = flat >> 8, col = flat & 255;
        const float4 f0 = *(const float4*)&vbase[row * Dn + col];
        const float4 f1 = *(const float4*)&vbase[row * Dn + col + 4];
        s16x8 p;
        p[0] = (short)f2bf(f0.x); p[1] = (short)f2bf(f0.y);
        p[2] = (short)f2bf(f0.z); p[3] = (short)f2bf(f0.w);
        p[4] = (short)f2bf(f1.x); p[5] = (short)f2bf(f1.y);
        p[6] = (short)f2bf(f1.z); p[7] = (short)f2bf(f1.w);
        *(s16x8*)&Al[row][col] = p;
    }

    f32x4 acc[16];
    #pragma unroll
    for (int ut = 0; ut < 16; ++ut) acc[ut] = (f32x4){0.f, 0.f, 0.f, 0.f};

    for (int kc = 0; kc < 8; ++kc) {
        const int k0 = kc * 32;
        // Stage B chunk: Bl[u][kk] = W1T[u][k0+kk]; LDS dest linear (lane*16),
        // per-lane global src — m97 pattern.
        #pragma unroll
        for (int j = 0; j < 4; ++j) {
            int flat = j * 256 + tid;
            const ushort* gsrc = W1T + (flat >> 2) * Dn + k0 + (flat & 3) * 8;
            ushort* ldst = &Bl[0][0] + (size_t)(j * 256 + (tid & ~63)) * 8;
            gload_lds16(gsrc, ldst);
        }
        __syncthreads();  // drains vmcnt (B ready) + lgkm (A ready on kc==0)

        const s16x8 af = *(const s16x8*)&Al[wid * 16 + l15][k0 + hi * 8];
        #pragma unroll
        for (int ut = 0; ut < 16; ++ut) {
            const s16x8 bf = *(const s16x8*)&Bl[ut * 16 + l15][hi * 8];
            acc[ut] = __builtin_amdgcn_mfma_f32_16x16x32_bf16(af, bf, acc[ut], 0, 0, 0);
        }
        __syncthreads();  // all waves done reading Bl before overwrite
    }

    // Epilogue: acc[ut][i] = proj[t = t0+wid*16+hi*4+i][u = ut*16+l15]  (m89 C/D layout)
    float ps[4] = {0.f, 0.f, 0.f, 0.f};
    #pragma unroll
    for (int ut = 0; ut < 16; ++ut) {
        #pragma unroll
        for (int i = 0; i < 4; ++i)
            ps[i] += fast_tanh(acc[ut][i] + qreg[ut]) * Vreg[ut];
    }
    const float bv = bV[0];
    #pragma unroll
    for (int i = 0; i < 4; ++i) {
        ps[i] += __shfl_xor(ps[i], 1, 64);
        ps[i] += __shfl_xor(ps[i], 2, 64);
        ps[i] += __shfl_xor(ps[i], 4, 64);
        ps[i] += __shfl_xor(ps[i], 8, 64);
        if (l15 == 0) scores[b * Tn + t0 + wid * 16 + hi * 4 + i] = ps[i] + bv;
    }
}

// K3: softmax over T per batch, in place.
__global__ __launch_bounds__(256) void k_softmax(const float* __restrict__ scores,
                                                 float* __restrict__ attn) {
    const int b = blockIdx.x, tid = threadIdx.x;
    __shared__ float redm[4];
    __shared__ float reds[4];
    float s[16];
    float m = -1e30f;
    #pragma unroll
    for (int k = 0; k < 16; ++k) {
        s[k] = scores[b * Tn + k * 256 + tid];
        m = fmaxf(m, s[k]);
    }
    #pragma unroll
    for (int off = 32; off > 0; off >>= 1) m = fmaxf(m, __shfl_xor(m, off, 64));
    const int wid = tid >> 6;
    if ((tid & 63) == 0) redm[wid] = m;
    __syncthreads();
    m = fmaxf(fmaxf(redm[0], redm[1]), fmaxf(redm[2], redm[3]));
    float sum = 0.f;
    #pragma unroll
    for (int k = 0; k < 16; ++k) { s[k] = __expf(s[k] - m); sum += s[k]; }
    #pragma unroll
    for (int off = 32; off > 0; off >>= 1) sum += __shfl_xor(sum, off, 64);
    if ((tid & 63) == 0) reds[wid] = sum;
    __syncthreads();
    sum = reds[0] + reds[1] + reds[2] + reds[3];
    const float inv = 1.0f / sum;
    #pragma unroll
    for (int k = 0; k < 16; ++k) attn[b * Tn + k * 256 + tid] = s[k] * inv;
}

// K4: context partials, CTX_C chunks per batch for occupancy. Deterministic.
__global__ __launch_bounds__(256) void k_ctx_partial(const float* __restrict__ values,
                                                     const float* __restrict__ attn,
                                                     float* __restrict__ partial) {
    const int c = blockIdx.x, b = blockIdx.y, tid = threadIdx.x;
    const int d4 = (tid & 63) * 4, tg = tid >> 6;
    float4 a = make_float4(0.f, 0.f, 0.f, 0.f);
    const float* vbase = values + (size_t)b * Tn * Dn;
    const int tstart = c * (Tn / CTX_C);
    for (int t = tstart + tg; t < tstart + Tn / CTX_C; t += 4) {
        const float w = attn[b * Tn + t];  // wave-uniform
        const float4 v = *(const float4*)&vbase[(size_t)t * Dn + d4];
        a.x += w * v.x; a.y += w * v.y; a.z += w * v.z; a.w += w * v.w;
    }
    __shared__ float4 red[4][64];
    red[tg][tid & 63] = a;
    __syncthreads();
    if (tg == 0) {
        const float4 r0 = red[0][tid], r1 = red[1][tid], r2 = red[2][tid], r3 = red[3][tid];
        a.x = r0.x + r1.x + r2.x + r3.x;
        a.y = r0.y + r1.y + r2.y + r3.y;
        a.z = r0.z + r1.z + r2.z + r3.z;
        a.w = r0.w + r1.w + r2.w + r3.w;
        *(float4*)&partial[((size_t)b * CTX_C + c) * Dn + d4] = a;
    }
}

// K5: reduce the CTX_C partials per batch.
__global__ __launch_bounds__(256) void k_ctx_final(const float* __restrict__ partial,
                                                   float* __restrict__ context) {
    const int b = blockIdx.x, d = threadIdx.x;
    float a = 0.f;
    #pragma unroll
    for (int c = 0; c < CTX_C; ++c) a += partial[((size_t)b * CTX_C + c) * Dn + d];
    context[b * Dn + d] = a;
}

extern "C" void kernel_launch(void* const* d_in, const int* in_sizes, int n_in,
                              void* d_out, int out_size, void* d_ws, size_t ws_size,
                              hipStream_t stream) {
    const float* query  = (const float*)d_in[0];
    const float* values = (const float*)d_in[1];
    const float* W1     = (const float*)d_in[2];
    const float* b1     = (const float*)d_in[3];
    const float* W2     = (const float*)d_in[4];
    const float* b2     = (const float*)d_in[5];
    const float* Vw     = (const float*)d_in[6];
    const float* bV     = (const float*)d_in[7];

    float* context = (float*)d_out;            // [B,D]
    float* attn    = (float*)d_out + Bn * Dn;  // [B,T,1] — score scratch then softmax in place
    float*  partial = (float*)d_ws;                         // [B, CTX_C, D] = 512 KB
    float*  qb      = partial + Bn * CTX_C * Dn;            // [B, U]        =  32 KB
    ushort* W1T     = (ushort*)(qb + Bn * Un);              // [U, D] bf16   = 128 KB

    k_w1t<<<dim3(Un), dim3(Dn), 0, stream>>>(W1, W1T);
    k_qproj<<<dim3(Bn), dim3(256), 0, stream>>>(query, W2, b1, b2, qb);
    k_score<<<dim3(Tn / 64, Bn), dim3(256), 0, stream>>>(values, W1T, qb, Vw, bV, attn);
    k_softmax<<<dim3(Bn), dim3(256), 0, stream>>>(attn, attn);
    k_ctx_partial<<<dim3(CTX_C, Bn), dim3(256), 0, stream>>>(values, attn, partial);
    k_ctx_final<<<dim3(Bn), dim3(256), 0, stream>>>(partial, context);
}